// Round 2
// baseline (2316.062 us; speedup 1.0000x reference)
//
#include <hip/hip_runtime.h>

// ---------------------------------------------------------------------------
// MultiLayerGNN: 2x GCNConv(128->128, ReLU) + Linear(128->64)
//   agg[dst] = disq[dst] * ( hs[dst] + sum_{edges src->dst} hs[src] ),
//   hs = (X @ W) * disq[row]   (self-loop folded into init of S)
// ---------------------------------------------------------------------------

static inline int cdiv_i(long long a, long long b) { return (int)((a + b - 1) / b); }

__device__ __forceinline__ long long load_idx(const void* p, long long i, int is64) {
  return is64 ? ((const long long*)p)[i] : (long long)((const int*)p)[i];
}

// Detect whether edge_index arrived as int64 (high words of first 64 entries all 0)
__global__ void k_detect(const void* __restrict__ eidx, int* __restrict__ flag) {
  if (blockIdx.x == 0 && threadIdx.x == 0) {
    const unsigned int* p = (const unsigned int*)eidx;
    int is64 = 1;
    for (int i = 0; i < 64; ++i) {
      if (p[2 * i + 1] != 0u) { is64 = 0; break; }
    }
    *flag = is64;
  }
}

__global__ void k_deg_init(float* __restrict__ deg, int n) {
  int i = blockIdx.x * 256 + threadIdx.x;
  if (i < n) deg[i] = 1.0f;  // self loop
}

__global__ void k_deg_edges(const void* __restrict__ eidx, const int* __restrict__ flag,
                            float* __restrict__ deg, int E) {
  int is64 = *flag;
  int e = blockIdx.x * 256 + threadIdx.x;
  if (e < E) {
    long long dst = load_idx(eidx, (long long)E + e, is64);
    atomicAdd(&deg[dst], 1.0f);
  }
}

__global__ void k_deg_rsqrt(float* __restrict__ deg, int n) {
  int i = blockIdx.x * 256 + threadIdx.x;
  if (i < n) deg[i] = rsqrtf(deg[i]);
}

// GEMM: H[row][c] = sum_k X[row][k] * W[k][c]  (+ epilogue)
// HIDDEN: scale by disq[row], write both H (gather source) and S (agg init = self loop)
// !HIDDEN: add bias, write H only (final output)
template <int COLS, bool HIDDEN>
__global__ __launch_bounds__(256) void k_gemm(
    const float* __restrict__ X, const float* __restrict__ W,
    const float* __restrict__ bias, const float* __restrict__ disq,
    float* __restrict__ H, float* __restrict__ S, int n) {
  __shared__ float Ws[128 * COLS];
  for (int i = threadIdx.x; i < 128 * COLS; i += 256) Ws[i] = W[i];
  __syncthreads();

  constexpr int TPR = COLS / 4;   // threads per row
  constexpr int RPB = 256 / TPR;  // rows per block
  int row = blockIdx.x * RPB + (int)threadIdx.x / TPR;
  int col = ((int)threadIdx.x % TPR) * 4;
  if (row >= n) return;

  const float4* xr = (const float4*)(X + (long long)row * 128);
  float4 acc = make_float4(0.f, 0.f, 0.f, 0.f);

#define GNN_STEP(AV, KK)                                   \
  {                                                        \
    float4 w = *(const float4*)&Ws[(KK) * COLS + col];     \
    acc.x = fmaf((AV), w.x, acc.x);                        \
    acc.y = fmaf((AV), w.y, acc.y);                        \
    acc.z = fmaf((AV), w.z, acc.z);                        \
    acc.w = fmaf((AV), w.w, acc.w);                        \
  }

#pragma unroll
  for (int k4 = 0; k4 < 32; ++k4) {
    float4 a4 = xr[k4];
    GNN_STEP(a4.x, k4 * 4 + 0)
    GNN_STEP(a4.y, k4 * 4 + 1)
    GNN_STEP(a4.z, k4 * 4 + 2)
    GNN_STEP(a4.w, k4 * 4 + 3)
  }
#undef GNN_STEP

  long long o = (long long)row * COLS + col;
  if (HIDDEN) {
    float s = disq[row];
    acc.x *= s; acc.y *= s; acc.z *= s; acc.w *= s;
    *(float4*)&H[o] = acc;
    *(float4*)&S[o] = acc;  // self-loop init of aggregator
  } else {
    const float4 b = *(const float4*)&bias[col];
    acc.x += b.x; acc.y += b.y; acc.z += b.z; acc.w += b.w;
    *(float4*)&H[o] = acc;
  }
}

// S[dst][c] += H[src][c]  — 32 lanes per edge, float4 per lane
__global__ __launch_bounds__(256) void k_scatter(const void* __restrict__ eidx,
                                                 const int* __restrict__ flag,
                                                 const float* __restrict__ H,
                                                 float* __restrict__ S, int E) {
  int is64 = *flag;
  long long gid = (long long)blockIdx.x * 256 + threadIdx.x;
  long long e = gid >> 5;          // 32 threads per edge
  int c4 = ((int)gid & 31) * 4;    // 4 channels per thread
  if (e >= E) return;
  long long src = load_idx(eidx, e, is64);
  long long dst = load_idx(eidx, (long long)E + e, is64);
  float4 v = *(const float4*)&H[src * 128 + c4];
  float* sp = &S[dst * 128 + c4];
  atomicAdd(sp + 0, v.x);
  atomicAdd(sp + 1, v.y);
  atomicAdd(sp + 2, v.z);
  atomicAdd(sp + 3, v.w);
}

// X2[i][c] = relu(disq[row] * S[i][c] + b[c]);  processes 4 elems/thread
__global__ __launch_bounds__(256) void k_finalize(const float* __restrict__ S,
                                                  const float* __restrict__ disq,
                                                  const float* __restrict__ bias,
                                                  float* __restrict__ X2, int n) {
  long long i4 = (long long)blockIdx.x * 256 + threadIdx.x;
  long long total4 = (long long)n * 128 / 4;
  if (i4 >= total4) return;
  long long i = i4 * 4;
  int row = (int)(i >> 7);
  int col = (int)(i & 127);
  float s = disq[row];
  float4 v = *(const float4*)&S[i];
  float4 b = *(const float4*)&bias[col];
  v.x = fmaxf(fmaf(s, v.x, b.x), 0.f);
  v.y = fmaxf(fmaf(s, v.y, b.y), 0.f);
  v.z = fmaxf(fmaf(s, v.z, b.z), 0.f);
  v.w = fmaxf(fmaf(s, v.w, b.w), 0.f);
  *(float4*)&X2[i] = v;
}

extern "C" void kernel_launch(void* const* d_in, const int* in_sizes, int n_in,
                              void* d_out, int out_size, void* d_ws, size_t ws_size,
                              hipStream_t stream) {
  (void)n_in; (void)out_size; (void)ws_size;
  const float* x  = (const float*)d_in[0];
  const void*  ei = d_in[1];
  const float* W1 = (const float*)d_in[2];
  const float* b1 = (const float*)d_in[3];
  const float* W2 = (const float*)d_in[4];
  const float* b2 = (const float*)d_in[5];
  const float* Wo = (const float*)d_in[6];
  const float* bo = (const float*)d_in[7];
  float* out = (float*)d_out;

  const int N = in_sizes[0] / 128;
  const int E = in_sizes[1] / 2;

  char* ws = (char*)d_ws;
  int* flag = (int*)ws;
  size_t off = 256;
  float* deg = (float*)(ws + off); off += ((size_t)N * 4 + 255) & ~(size_t)255;
  float* H   = (float*)(ws + off); off += (size_t)N * 128 * 4;
  float* S   = (float*)(ws + off); off += (size_t)N * 128 * 4;
  float* X2  = (float*)(ws + off); off += (size_t)N * 128 * 4;

  k_detect<<<1, 64, 0, stream>>>(ei, flag);
  k_deg_init<<<cdiv_i(N, 256), 256, 0, stream>>>(deg, N);
  k_deg_edges<<<cdiv_i(E, 256), 256, 0, stream>>>(ei, flag, deg, E);
  k_deg_rsqrt<<<cdiv_i(N, 256), 256, 0, stream>>>(deg, N);

  const int scatter_blocks = cdiv_i((long long)E * 32, 256);
  const int fin_blocks = cdiv_i((long long)N * 128 / 4, 256);

  // Layer 1
  k_gemm<128, true><<<cdiv_i(N, 8), 256, 0, stream>>>(x, W1, nullptr, deg, H, S, N);
  k_scatter<<<scatter_blocks, 256, 0, stream>>>(ei, flag, H, S, E);
  k_finalize<<<fin_blocks, 256, 0, stream>>>(S, deg, b1, X2, N);

  // Layer 2
  k_gemm<128, true><<<cdiv_i(N, 8), 256, 0, stream>>>(X2, W2, nullptr, deg, H, S, N);
  k_scatter<<<scatter_blocks, 256, 0, stream>>>(ei, flag, H, S, E);
  k_finalize<<<fin_blocks, 256, 0, stream>>>(S, deg, b2, X2, N);

  // Output layer
  k_gemm<64, false><<<cdiv_i(N, 16), 256, 0, stream>>>(X2, Wo, bo, nullptr, out, nullptr, N);
}

// Round 5
// 506.390 us; speedup vs baseline: 4.5737x; 4.5737x over previous
//
#include <hip/hip_runtime.h>

// ---------------------------------------------------------------------------
// MultiLayerGNN: 2x GCNConv(128->128, ReLU) + Linear(128->64)
// Pull-mode aggregation via per-launch CSR build (no float atomics):
//   hs = (X @ W) * disq[row]
//   X2[dst] = relu( disq[dst] * ( hs[dst] + sum_{src->dst} hs[src] ) + b )
// ---------------------------------------------------------------------------

static inline int cdiv_i(long long a, long long b) { return (int)((a + b - 1) / b); }

__device__ __forceinline__ long long load_idx(const void* p, long long i, int is64) {
  return is64 ? ((const long long*)p)[i] : (long long)((const int*)p)[i];
}

// Detect whether edge_index arrived as int64 (high words of first 64 entries all 0)
__global__ void k_detect(const void* __restrict__ eidx, int* __restrict__ flag) {
  if (blockIdx.x == 0 && threadIdx.x == 0) {
    const unsigned int* p = (const unsigned int*)eidx;
    int is64 = 1;
    for (int i = 0; i < 64; ++i) {
      if (p[2 * i + 1] != 0u) { is64 = 0; break; }
    }
    *flag = is64;
  }
}

__global__ void k_zero2(int* __restrict__ a, int* __restrict__ b, int n) {
  int i = blockIdx.x * 256 + threadIdx.x;
  if (i < n) { a[i] = 0; b[i] = 0; }
}

// in-degree histogram (int atomics; ~12-way avg contention, cheap)
__global__ void k_hist(const void* __restrict__ eidx, const int* __restrict__ flag,
                       int* __restrict__ counts, int E) {
  int is64 = *flag;
  int e = blockIdx.x * 256 + threadIdx.x;
  if (e < E) {
    long long dst = load_idx(eidx, (long long)E + e, is64);
    atomicAdd(&counts[dst], 1);
  }
}

__global__ void k_disq(const int* __restrict__ counts, float* __restrict__ disq, int n) {
  int i = blockIdx.x * 256 + threadIdx.x;
  if (i < n) disq[i] = rsqrtf(1.0f + (float)counts[i]);  // +1 = self loop
}

// per-256-block inclusive scan -> exclusive offsets + block totals
__global__ __launch_bounds__(256) void k_scan_local(const int* __restrict__ counts,
                                                    int* __restrict__ offsets,
                                                    int* __restrict__ partials, int n) {
  __shared__ int sd[256];
  int tid = threadIdx.x;
  int i = blockIdx.x * 256 + tid;
  int v = (i < n) ? counts[i] : 0;
  sd[tid] = v;
  __syncthreads();
  for (int off = 1; off < 256; off <<= 1) {
    int t = (tid >= off) ? sd[tid - off] : 0;
    __syncthreads();
    sd[tid] += t;
    __syncthreads();
  }
  if (i < n) offsets[i] = sd[tid] - v;  // exclusive
  if (tid == 255) partials[blockIdx.x] = sd[255];
}

// single-block scan of block totals (in place, exclusive), chunked with carry
__global__ __launch_bounds__(256) void k_scan_partials(int* __restrict__ partials, int nblk) {
  __shared__ int sd[256];
  __shared__ int carry_s;
  int tid = threadIdx.x;
  if (tid == 0) carry_s = 0;
  __syncthreads();
  for (int base = 0; base < nblk; base += 256) {
    int i = base + tid;
    int v = (i < nblk) ? partials[i] : 0;
    sd[tid] = v;
    __syncthreads();
    for (int off = 1; off < 256; off <<= 1) {
      int t = (tid >= off) ? sd[tid - off] : 0;
      __syncthreads();
      sd[tid] += t;
      __syncthreads();
    }
    int carry = carry_s;
    if (i < nblk) partials[i] = carry + sd[tid] - v;  // exclusive
    __syncthreads();
    if (tid == 0) carry_s = carry + sd[255];
    __syncthreads();
  }
}

__global__ void k_scan_add(int* __restrict__ offsets, const int* __restrict__ partials, int n) {
  int i = blockIdx.x * 256 + threadIdx.x;
  if (i < n) offsets[i] += partials[blockIdx.x];
}

// scatter edge ids into dst buckets
__global__ void k_fill(const void* __restrict__ eidx, const int* __restrict__ flag,
                       const int* __restrict__ offsets, int* __restrict__ cursor,
                       int* __restrict__ csr_src, int E) {
  int is64 = *flag;
  int e = blockIdx.x * 256 + threadIdx.x;
  if (e < E) {
    long long src = load_idx(eidx, e, is64);
    long long dst = load_idx(eidx, (long long)E + e, is64);
    int pos = offsets[dst] + atomicAdd(&cursor[dst], 1);
    csr_src[pos] = (int)src;
  }
}

// H[row] = (X[row] @ W) * disq[row]; 128 cols, 2 rows/thread (reuse each LDS read)
__global__ __launch_bounds__(256) void k_gemm128(const float* __restrict__ X,
                                                 const float* __restrict__ W,
                                                 const float* __restrict__ disq,
                                                 float* __restrict__ H, int n) {
  __shared__ float Ws[128 * 128];
  {
    const float4* Wv = (const float4*)W;
    float4* Wsv = (float4*)Ws;
    for (int i = threadIdx.x; i < 4096; i += 256) Wsv[i] = Wv[i];
  }
  __syncthreads();

  int col = ((int)threadIdx.x & 31) * 4;
  int row = blockIdx.x * 16 + ((int)threadIdx.x >> 5) * 2;
  if (row >= n) return;
  bool has2 = (row + 1) < n;

  const float4* x0 = (const float4*)(X + (long long)row * 128);
  const float4* x1 = (const float4*)(X + (long long)(row + (has2 ? 1 : 0)) * 128);
  float4 acc0 = make_float4(0.f, 0.f, 0.f, 0.f);
  float4 acc1 = make_float4(0.f, 0.f, 0.f, 0.f);

#pragma unroll
  for (int k4 = 0; k4 < 32; ++k4) {
    float4 a0 = x0[k4];
    float4 a1 = x1[k4];
#pragma unroll
    for (int kk = 0; kk < 4; ++kk) {
      float av0 = (&a0.x)[kk];
      float av1 = (&a1.x)[kk];
      float4 w = *(const float4*)&Ws[(k4 * 4 + kk) * 128 + col];
      acc0.x = fmaf(av0, w.x, acc0.x);
      acc0.y = fmaf(av0, w.y, acc0.y);
      acc0.z = fmaf(av0, w.z, acc0.z);
      acc0.w = fmaf(av0, w.w, acc0.w);
      acc1.x = fmaf(av1, w.x, acc1.x);
      acc1.y = fmaf(av1, w.y, acc1.y);
      acc1.z = fmaf(av1, w.z, acc1.z);
      acc1.w = fmaf(av1, w.w, acc1.w);
    }
  }

  float s0 = disq[row];
  acc0.x *= s0; acc0.y *= s0; acc0.z *= s0; acc0.w *= s0;
  *(float4*)&H[(long long)row * 128 + col] = acc0;
  if (has2) {
    float s1 = disq[row + 1];
    acc1.x *= s1; acc1.y *= s1; acc1.z *= s1; acc1.w *= s1;
    *(float4*)&H[(long long)(row + 1) * 128 + col] = acc1;
  }
}

// pull aggregation: one wave per dst, float2 per lane (128 ch / 64 lanes)
__global__ __launch_bounds__(256) void k_aggregate(
    const float* __restrict__ H, const int* __restrict__ csr_src,
    const int* __restrict__ offsets, const int* __restrict__ counts,
    const float* __restrict__ disq, const float* __restrict__ bias,
    float* __restrict__ X2, int n) {
  int dst = blockIdx.x * 4 + ((int)threadIdx.x >> 6);
  if (dst >= n) return;
  int lane = threadIdx.x & 63;
  int c = lane * 2;

  float2 acc = *(const float2*)&H[(long long)dst * 128 + c];  // self loop
  int beg = offsets[dst];
  int cnt = counts[dst];

  int navail = cnt < 64 ? cnt : 64;
  int myidx = (lane < navail) ? csr_src[beg + lane] : 0;

  int j = 0;
  for (; j + 4 <= navail; j += 4) {
    int s0 = __shfl(myidx, j, 64);
    int s1 = __shfl(myidx, j + 1, 64);
    int s2 = __shfl(myidx, j + 2, 64);
    int s3 = __shfl(myidx, j + 3, 64);
    float2 v0 = *(const float2*)&H[(long long)s0 * 128 + c];
    float2 v1 = *(const float2*)&H[(long long)s1 * 128 + c];
    float2 v2 = *(const float2*)&H[(long long)s2 * 128 + c];
    float2 v3 = *(const float2*)&H[(long long)s3 * 128 + c];
    acc.x += v0.x + v1.x + v2.x + v3.x;
    acc.y += v0.y + v1.y + v2.y + v3.y;
  }
  for (; j < navail; ++j) {
    int s = __shfl(myidx, j, 64);
    float2 v = *(const float2*)&H[(long long)s * 128 + c];
    acc.x += v.x;
    acc.y += v.y;
  }
  // degree > 64 fallback (astronomically unlikely for random graphs; correctness)
  for (int jj = beg + 64; jj < beg + cnt; ++jj) {
    int s = csr_src[jj];
    float2 v = *(const float2*)&H[(long long)s * 128 + c];
    acc.x += v.x;
    acc.y += v.y;
  }

  float s = disq[dst];
  float2 b = *(const float2*)&bias[c];
  float rx = fmaxf(fmaf(s, acc.x, b.x), 0.f);
  float ry = fmaxf(fmaf(s, acc.y, b.y), 0.f);
  float2 r; r.x = rx; r.y = ry;
  *(float2*)&X2[(long long)dst * 128 + c] = r;
}

// final GEMM: out[row] = X[row] @ Wo + bo  (64 cols)
__global__ __launch_bounds__(256) void k_gemm64(const float* __restrict__ X,
                                                const float* __restrict__ W,
                                                const float* __restrict__ bias,
                                                float* __restrict__ out, int n) {
  __shared__ float Ws[128 * 64];
  {
    const float4* Wv = (const float4*)W;
    float4* Wsv = (float4*)Ws;
    for (int i = threadIdx.x; i < 2048; i += 256) Wsv[i] = Wv[i];
  }
  __syncthreads();

  int col = ((int)threadIdx.x & 15) * 4;
  int row = blockIdx.x * 16 + ((int)threadIdx.x >> 4);
  if (row >= n) return;

  const float4* xr = (const float4*)(X + (long long)row * 128);
  float4 acc = make_float4(0.f, 0.f, 0.f, 0.f);
#pragma unroll
  for (int k4 = 0; k4 < 32; ++k4) {
    float4 a4 = xr[k4];
#pragma unroll
    for (int kk = 0; kk < 4; ++kk) {
      float av = (&a4.x)[kk];
      float4 w = *(const float4*)&Ws[(k4 * 4 + kk) * 64 + col];
      acc.x = fmaf(av, w.x, acc.x);
      acc.y = fmaf(av, w.y, acc.y);
      acc.z = fmaf(av, w.z, acc.z);
      acc.w = fmaf(av, w.w, acc.w);
    }
  }
  const float4 b = *(const float4*)&bias[col];
  acc.x += b.x; acc.y += b.y; acc.z += b.z; acc.w += b.w;
  *(float4*)&out[(long long)row * 64 + col] = acc;
}

extern "C" void kernel_launch(void* const* d_in, const int* in_sizes, int n_in,
                              void* d_out, int out_size, void* d_ws, size_t ws_size,
                              hipStream_t stream) {
  (void)n_in; (void)out_size; (void)ws_size;
  const float* x  = (const float*)d_in[0];
  const void*  ei = d_in[1];
  const float* W1 = (const float*)d_in[2];
  const float* b1 = (const float*)d_in[3];
  const float* W2 = (const float*)d_in[4];
  const float* b2 = (const float*)d_in[5];
  const float* Wo = (const float*)d_in[6];
  const float* bo = (const float*)d_in[7];
  float* out = (float*)d_out;

  const int N = in_sizes[0] / 128;
  const int E = in_sizes[1] / 2;
  const int nblk_n = cdiv_i(N, 256);

  char* ws = (char*)d_ws;
  size_t off = 0;
  auto alloc = [&](size_t bytes) {
    void* p = ws + off;
    off += (bytes + 255) & ~(size_t)255;
    return p;
  };
  int*   flag     = (int*)alloc(4);
  int*   counts   = (int*)alloc((size_t)N * 4);
  int*   cursor   = (int*)alloc((size_t)N * 4);
  int*   offsets  = (int*)alloc((size_t)N * 4);
  int*   partials = (int*)alloc((size_t)nblk_n * 4);
  float* disq     = (float*)alloc((size_t)N * 4);
  int*   csr_src  = (int*)alloc((size_t)E * 4);
  float* H        = (float*)alloc((size_t)N * 128 * 4);
  float* X2       = (float*)alloc((size_t)N * 128 * 4);

  // --- CSR build + normalization ---
  k_detect<<<1, 64, 0, stream>>>(ei, flag);
  k_zero2<<<nblk_n, 256, 0, stream>>>(counts, cursor, N);
  k_hist<<<cdiv_i(E, 256), 256, 0, stream>>>(ei, flag, counts, E);
  k_disq<<<nblk_n, 256, 0, stream>>>(counts, disq, N);
  k_scan_local<<<nblk_n, 256, 0, stream>>>(counts, offsets, partials, N);
  k_scan_partials<<<1, 256, 0, stream>>>(partials, nblk_n);
  k_scan_add<<<nblk_n, 256, 0, stream>>>(offsets, partials, N);
  k_fill<<<cdiv_i(E, 256), 256, 0, stream>>>(ei, flag, offsets, cursor, csr_src, E);

  const int gemm128_blocks = cdiv_i(N, 16);
  const int agg_blocks = cdiv_i(N, 4);

  // Layer 1
  k_gemm128<<<gemm128_blocks, 256, 0, stream>>>(x, W1, disq, H, N);
  k_aggregate<<<agg_blocks, 256, 0, stream>>>(H, csr_src, offsets, counts, disq, b1, X2, N);
  // Layer 2
  k_gemm128<<<gemm128_blocks, 256, 0, stream>>>(X2, W2, disq, H, N);
  k_aggregate<<<agg_blocks, 256, 0, stream>>>(H, csr_src, offsets, counts, disq, b2, X2, N);
  // Output layer
  k_gemm64<<<cdiv_i(N, 16), 256, 0, stream>>>(X2, Wo, bo, out, N);
}

// Round 6
// 335.685 us; speedup vs baseline: 6.8995x; 1.5085x over previous
//
#include <hip/hip_runtime.h>

// ---------------------------------------------------------------------------
// MultiLayerGNN: 2x GCNConv(128->128, ReLU) + Linear(128->64)
// Pull-mode aggregation via per-launch CSR build (no float atomics).
// GEMM: X-tile transposed in LDS (broadcast b128 reads), W via L1/L2.
// ---------------------------------------------------------------------------

static inline int cdiv_i(long long a, long long b) { return (int)((a + b - 1) / b); }

__device__ __forceinline__ long long load_idx(const void* p, long long i, int is64) {
  return is64 ? ((const long long*)p)[i] : (long long)((const int*)p)[i];
}

// Detect whether edge_index arrived as int64 (high words of first 64 entries all 0)
__global__ void k_detect(const void* __restrict__ eidx, int* __restrict__ flag) {
  if (blockIdx.x == 0 && threadIdx.x == 0) {
    const unsigned int* p = (const unsigned int*)eidx;
    int is64 = 1;
    for (int i = 0; i < 64; ++i) {
      if (p[2 * i + 1] != 0u) { is64 = 0; break; }
    }
    *flag = is64;
  }
}

__global__ void k_zero2(int* __restrict__ a, int* __restrict__ b, int n) {
  int i = blockIdx.x * 256 + threadIdx.x;
  if (i < n) { a[i] = 0; b[i] = 0; }
}

__global__ void k_hist(const void* __restrict__ eidx, const int* __restrict__ flag,
                       int* __restrict__ counts, int E) {
  int is64 = *flag;
  int e = blockIdx.x * 256 + threadIdx.x;
  if (e < E) {
    long long dst = load_idx(eidx, (long long)E + e, is64);
    atomicAdd(&counts[dst], 1);
  }
}

__global__ void k_disq(const int* __restrict__ counts, float* __restrict__ disq, int n) {
  int i = blockIdx.x * 256 + threadIdx.x;
  if (i < n) disq[i] = rsqrtf(1.0f + (float)counts[i]);  // +1 = self loop
}

__global__ __launch_bounds__(256) void k_scan_local(const int* __restrict__ counts,
                                                    int* __restrict__ offsets,
                                                    int* __restrict__ partials, int n) {
  __shared__ int sd[256];
  int tid = threadIdx.x;
  int i = blockIdx.x * 256 + tid;
  int v = (i < n) ? counts[i] : 0;
  sd[tid] = v;
  __syncthreads();
  for (int off = 1; off < 256; off <<= 1) {
    int t = (tid >= off) ? sd[tid - off] : 0;
    __syncthreads();
    sd[tid] += t;
    __syncthreads();
  }
  if (i < n) offsets[i] = sd[tid] - v;  // exclusive
  if (tid == 255) partials[blockIdx.x] = sd[255];
}

__global__ __launch_bounds__(256) void k_scan_partials(int* __restrict__ partials, int nblk) {
  __shared__ int sd[256];
  __shared__ int carry_s;
  int tid = threadIdx.x;
  if (tid == 0) carry_s = 0;
  __syncthreads();
  for (int base = 0; base < nblk; base += 256) {
    int i = base + tid;
    int v = (i < nblk) ? partials[i] : 0;
    sd[tid] = v;
    __syncthreads();
    for (int off = 1; off < 256; off <<= 1) {
      int t = (tid >= off) ? sd[tid - off] : 0;
      __syncthreads();
      sd[tid] += t;
      __syncthreads();
    }
    int carry = carry_s;
    if (i < nblk) partials[i] = carry + sd[tid] - v;  // exclusive
    __syncthreads();
    if (tid == 0) carry_s = carry + sd[255];
    __syncthreads();
  }
}

__global__ void k_scan_add(int* __restrict__ offsets, const int* __restrict__ partials, int n) {
  int i = blockIdx.x * 256 + threadIdx.x;
  if (i < n) offsets[i] += partials[blockIdx.x];
}

__global__ void k_fill(const void* __restrict__ eidx, const int* __restrict__ flag,
                       const int* __restrict__ offsets, int* __restrict__ cursor,
                       int* __restrict__ csr_src, int E) {
  int is64 = *flag;
  int e = blockIdx.x * 256 + threadIdx.x;
  if (e < E) {
    long long src = load_idx(eidx, e, is64);
    long long dst = load_idx(eidx, (long long)E + e, is64);
    int pos = offsets[dst] + atomicAdd(&cursor[dst], 1);
    csr_src[pos] = (int)src;
  }
}

// ---------------------------------------------------------------------------
// GEMM, K=128 fixed. Block covers ROWS rows x COLS cols.
// LDS: X-tile transposed Xs[k][row] (+pad) -> compute reads are b128 broadcasts.
// W read from global (64/32 KB, L1/L2-resident; lanes coalesce/broadcast).
// Thread = 4 rows x 4 cols; per k: 1 ds_read_b128 + 1 global float4 + 16 FMA.
// ---------------------------------------------------------------------------
template <int COLS, int ROWS, bool HIDDEN>
__global__ __launch_bounds__(256, 4) void k_gemm_t(
    const float* __restrict__ X, const float* __restrict__ W,
    const float* __restrict__ disq, const float* __restrict__ bias,
    float* __restrict__ H, int n) {
  constexpr int CT = COLS / 4;   // col-threads (32 or 16)
  constexpr int PAD = 4;         // keep 16B alignment, spread banks
  __shared__ float Xs[128][ROWS + PAD];

  const int row0 = blockIdx.x * ROWS;

  // --- stage X[row0 .. row0+ROWS) transposed ---
  {
    constexpr int KT = 256 / ROWS;   // threads per row (8 for ROWS=32, 4 for 64)
    constexpr int NL4 = 32 / KT;     // float4 loads per thread
    const int srow = (int)threadIdx.x / KT;
    const int skq = (int)threadIdx.x % KT;
    const int grow = row0 + srow;
    const bool valid = grow < n;
    const float4* xg = (const float4*)(X + (long long)grow * 128);
#pragma unroll
    for (int i = 0; i < NL4; ++i) {
      int k4 = skq + i * KT;  // float4 index along K
      float4 v = valid ? xg[k4] : make_float4(0.f, 0.f, 0.f, 0.f);
      Xs[k4 * 4 + 0][srow] = v.x;
      Xs[k4 * 4 + 1][srow] = v.y;
      Xs[k4 * 4 + 2][srow] = v.z;
      Xs[k4 * 4 + 3][srow] = v.w;
    }
  }
  __syncthreads();

  const int c0 = ((int)threadIdx.x % CT) * 4;
  const int r0 = ((int)threadIdx.x / CT) * 4;

  float acc[4][4] = {};
#pragma unroll 8
  for (int k = 0; k < 128; ++k) {
    const float4 xr = *(const float4*)&Xs[k][r0];
    const float4 w = *(const float4*)&W[k * COLS + c0];
#pragma unroll
    for (int i = 0; i < 4; ++i) {
      float a = (&xr.x)[i];
      acc[i][0] = fmaf(a, w.x, acc[i][0]);
      acc[i][1] = fmaf(a, w.y, acc[i][1]);
      acc[i][2] = fmaf(a, w.z, acc[i][2]);
      acc[i][3] = fmaf(a, w.w, acc[i][3]);
    }
  }

#pragma unroll
  for (int i = 0; i < 4; ++i) {
    int row = row0 + r0 + i;
    if (row < n) {
      float4 o = make_float4(acc[i][0], acc[i][1], acc[i][2], acc[i][3]);
      if (HIDDEN) {
        float s = disq[row];
        o.x *= s; o.y *= s; o.z *= s; o.w *= s;
      } else {
        const float4 b = *(const float4*)&bias[c0];
        o.x += b.x; o.y += b.y; o.z += b.z; o.w += b.w;
      }
      *(float4*)&H[(long long)row * COLS + c0] = o;
    }
  }
}

// pull aggregation: one wave per dst, float2 per lane (128 ch / 64 lanes)
__global__ __launch_bounds__(256) void k_aggregate(
    const float* __restrict__ H, const int* __restrict__ csr_src,
    const int* __restrict__ offsets, const int* __restrict__ counts,
    const float* __restrict__ disq, const float* __restrict__ bias,
    float* __restrict__ X2, int n) {
  int dst = blockIdx.x * 4 + ((int)threadIdx.x >> 6);
  if (dst >= n) return;
  int lane = threadIdx.x & 63;
  int c = lane * 2;

  float2 acc = *(const float2*)&H[(long long)dst * 128 + c];  // self loop
  int beg = offsets[dst];
  int cnt = counts[dst];

  int navail = cnt < 64 ? cnt : 64;
  int myidx = (lane < navail) ? csr_src[beg + lane] : 0;

  int j = 0;
  for (; j + 4 <= navail; j += 4) {
    int s0 = __shfl(myidx, j, 64);
    int s1 = __shfl(myidx, j + 1, 64);
    int s2 = __shfl(myidx, j + 2, 64);
    int s3 = __shfl(myidx, j + 3, 64);
    float2 v0 = *(const float2*)&H[(long long)s0 * 128 + c];
    float2 v1 = *(const float2*)&H[(long long)s1 * 128 + c];
    float2 v2 = *(const float2*)&H[(long long)s2 * 128 + c];
    float2 v3 = *(const float2*)&H[(long long)s3 * 128 + c];
    acc.x += v0.x + v1.x + v2.x + v3.x;
    acc.y += v0.y + v1.y + v2.y + v3.y;
  }
  for (; j < navail; ++j) {
    int s = __shfl(myidx, j, 64);
    float2 v = *(const float2*)&H[(long long)s * 128 + c];
    acc.x += v.x;
    acc.y += v.y;
  }
  for (int jj = beg + 64; jj < beg + cnt; ++jj) {  // degree>64 fallback
    int s = csr_src[jj];
    float2 v = *(const float2*)&H[(long long)s * 128 + c];
    acc.x += v.x;
    acc.y += v.y;
  }

  float s = disq[dst];
  float2 b = *(const float2*)&bias[c];
  float2 r;
  r.x = fmaxf(fmaf(s, acc.x, b.x), 0.f);
  r.y = fmaxf(fmaf(s, acc.y, b.y), 0.f);
  *(float2*)&X2[(long long)dst * 128 + c] = r;
}

extern "C" void kernel_launch(void* const* d_in, const int* in_sizes, int n_in,
                              void* d_out, int out_size, void* d_ws, size_t ws_size,
                              hipStream_t stream) {
  (void)n_in; (void)out_size; (void)ws_size;
  const float* x  = (const float*)d_in[0];
  const void*  ei = d_in[1];
  const float* W1 = (const float*)d_in[2];
  const float* b1 = (const float*)d_in[3];
  const float* W2 = (const float*)d_in[4];
  const float* b2 = (const float*)d_in[5];
  const float* Wo = (const float*)d_in[6];
  const float* bo = (const float*)d_in[7];
  float* out = (float*)d_out;

  const int N = in_sizes[0] / 128;
  const int E = in_sizes[1] / 2;
  const int nblk_n = cdiv_i(N, 256);

  char* ws = (char*)d_ws;
  size_t off = 0;
  auto alloc = [&](size_t bytes) {
    void* p = ws + off;
    off += (bytes + 255) & ~(size_t)255;
    return p;
  };
  int*   flag     = (int*)alloc(4);
  int*   counts   = (int*)alloc((size_t)N * 4);
  int*   cursor   = (int*)alloc((size_t)N * 4);
  int*   offsets  = (int*)alloc((size_t)N * 4);
  int*   partials = (int*)alloc((size_t)nblk_n * 4);
  float* disq     = (float*)alloc((size_t)N * 4);
  int*   csr_src  = (int*)alloc((size_t)E * 4);
  float* H        = (float*)alloc((size_t)N * 128 * 4);
  float* X2       = (float*)alloc((size_t)N * 128 * 4);

  // --- CSR build + normalization ---
  k_detect<<<1, 64, 0, stream>>>(ei, flag);
  k_zero2<<<nblk_n, 256, 0, stream>>>(counts, cursor, N);
  k_hist<<<cdiv_i(E, 256), 256, 0, stream>>>(ei, flag, counts, E);
  k_disq<<<nblk_n, 256, 0, stream>>>(counts, disq, N);
  k_scan_local<<<nblk_n, 256, 0, stream>>>(counts, offsets, partials, N);
  k_scan_partials<<<1, 256, 0, stream>>>(partials, nblk_n);
  k_scan_add<<<nblk_n, 256, 0, stream>>>(offsets, partials, N);
  k_fill<<<cdiv_i(E, 256), 256, 0, stream>>>(ei, flag, offsets, cursor, csr_src, E);

  const int agg_blocks = cdiv_i(N, 4);

  // Layer 1: 128-col GEMM, 32-row tiles
  k_gemm_t<128, 32, true><<<cdiv_i(N, 32), 256, 0, stream>>>(x, W1, disq, b1, H, N);
  k_aggregate<<<agg_blocks, 256, 0, stream>>>(H, csr_src, offsets, counts, disq, b1, X2, N);
  // Layer 2
  k_gemm_t<128, 32, true><<<cdiv_i(N, 32), 256, 0, stream>>>(X2, W2, disq, b2, H, N);
  k_aggregate<<<agg_blocks, 256, 0, stream>>>(H, csr_src, offsets, counts, disq, b2, X2, N);
  // Output layer: 64-col GEMM, 64-row tiles
  k_gemm_t<64, 64, false><<<cdiv_i(N, 64), 256, 0, stream>>>(X2, Wo, nullptr, bo, out, N);
}

// Round 14
// 291.079 us; speedup vs baseline: 7.9568x; 1.1532x over previous
//
#include <hip/hip_runtime.h>
#include <hip/hip_fp16.h>

// ---------------------------------------------------------------------------
// MultiLayerGNN: 2x GCNConv(128->128, ReLU) + Linear(128->64)
// CSR pull-mode aggregation; H stored fp16 (halves gather BW); GEMM with
// X-tile transposed in LDS, 8 rows x 4 cols per thread (W L1 amortized).
// ---------------------------------------------------------------------------

static inline int cdiv_i(long long a, long long b) { return (int)((a + b - 1) / b); }

__device__ __forceinline__ long long load_idx(const void* p, long long i, int is64) {
  return is64 ? ((const long long*)p)[i] : (long long)((const int*)p)[i];
}

__global__ void k_detect(const void* __restrict__ eidx, int* __restrict__ flag) {
  if (blockIdx.x == 0 && threadIdx.x == 0) {
    const unsigned int* p = (const unsigned int*)eidx;
    int is64 = 1;
    for (int i = 0; i < 64; ++i) {
      if (p[2 * i + 1] != 0u) { is64 = 0; break; }
    }
    *flag = is64;
  }
}

__global__ void k_zero2(int* __restrict__ a, int* __restrict__ b, int n) {
  int i = blockIdx.x * 256 + threadIdx.x;
  if (i < n) { a[i] = 0; b[i] = 0; }
}

__global__ void k_hist(const void* __restrict__ eidx, const int* __restrict__ flag,
                       int* __restrict__ counts, int E) {
  int is64 = *flag;
  int e = blockIdx.x * 256 + threadIdx.x;
  if (e < E) {
    long long dst = load_idx(eidx, (long long)E + e, is64);
    atomicAdd(&counts[dst], 1);
  }
}

__global__ void k_disq(const int* __restrict__ counts, float* __restrict__ disq, int n) {
  int i = blockIdx.x * 256 + threadIdx.x;
  if (i < n) disq[i] = rsqrtf(1.0f + (float)counts[i]);  // +1 = self loop
}

__global__ __launch_bounds__(256) void k_scan_local(const int* __restrict__ counts,
                                                    int* __restrict__ offsets,
                                                    int* __restrict__ partials, int n) {
  __shared__ int sd[256];
  int tid = threadIdx.x;
  int i = blockIdx.x * 256 + tid;
  int v = (i < n) ? counts[i] : 0;
  sd[tid] = v;
  __syncthreads();
  for (int off = 1; off < 256; off <<= 1) {
    int t = (tid >= off) ? sd[tid - off] : 0;
    __syncthreads();
    sd[tid] += t;
    __syncthreads();
  }
  if (i < n) offsets[i] = sd[tid] - v;  // exclusive
  if (tid == 255) partials[blockIdx.x] = sd[255];
}

__global__ __launch_bounds__(256) void k_scan_partials(int* __restrict__ partials, int nblk) {
  __shared__ int sd[256];
  __shared__ int carry_s;
  int tid = threadIdx.x;
  if (tid == 0) carry_s = 0;
  __syncthreads();
  for (int base = 0; base < nblk; base += 256) {
    int i = base + tid;
    int v = (i < nblk) ? partials[i] : 0;
    sd[tid] = v;
    __syncthreads();
    for (int off = 1; off < 256; off <<= 1) {
      int t = (tid >= off) ? sd[tid - off] : 0;
      __syncthreads();
      sd[tid] += t;
      __syncthreads();
    }
    int carry = carry_s;
    if (i < nblk) partials[i] = carry + sd[tid] - v;  // exclusive
    __syncthreads();
    if (tid == 0) carry_s = carry + sd[255];
    __syncthreads();
  }
}

__global__ void k_scan_add(int* __restrict__ offsets, const int* __restrict__ partials, int n) {
  int i = blockIdx.x * 256 + threadIdx.x;
  if (i < n) offsets[i] += partials[blockIdx.x];
}

__global__ void k_fill(const void* __restrict__ eidx, const int* __restrict__ flag,
                       const int* __restrict__ offsets, int* __restrict__ cursor,
                       int* __restrict__ csr_src, int E) {
  int is64 = *flag;
  int e = blockIdx.x * 256 + threadIdx.x;
  if (e < E) {
    long long src = load_idx(eidx, e, is64);
    long long dst = load_idx(eidx, (long long)E + e, is64);
    int pos = offsets[dst] + atomicAdd(&cursor[dst], 1);
    csr_src[pos] = (int)src;
  }
}

// ---------------------------------------------------------------------------
// GEMM, K=128. Block = ROWS rows x COLS cols; thread = RPT rows x 4 cols.
// X-tile transposed in LDS (b128 broadcast reads); W streamed from L1/L2.
// HIDDEN: out = fp16 H[(row)*(COLS/2)] scaled by disq; else f32 + bias.
// ---------------------------------------------------------------------------
template <int COLS, int ROWS, bool HIDDEN>
__global__ __launch_bounds__(256, 4) void k_gemm_t(
    const float* __restrict__ X, const float* __restrict__ W,
    const float* __restrict__ disq, const float* __restrict__ bias,
    void* __restrict__ OUT, int n) {
  constexpr int CT = COLS / 4;    // col-thread groups (32 / 16)
  constexpr int RG = 256 / CT;    // row groups (8 / 16)
  constexpr int RPT = ROWS / RG;  // rows per thread (8)
  constexpr int PAD = 4;
  __shared__ float Xs[128][ROWS + PAD];

  const int row0 = blockIdx.x * ROWS;

  // stage X[row0 .. row0+ROWS) transposed
  {
    constexpr int KT = 256 / ROWS;  // threads per row (4 for 64, 2 for 128)
    constexpr int NL4 = 32 / KT;    // float4 loads per thread
    const int srow = (int)threadIdx.x / KT;
    const int skq = (int)threadIdx.x % KT;
    const int grow = row0 + srow;
    const bool valid = grow < n;
    const float4* xg = (const float4*)(X + (long long)grow * 128);
#pragma unroll
    for (int i = 0; i < NL4; ++i) {
      int k4 = skq + i * KT;
      float4 v = valid ? xg[k4] : make_float4(0.f, 0.f, 0.f, 0.f);
      Xs[k4 * 4 + 0][srow] = v.x;
      Xs[k4 * 4 + 1][srow] = v.y;
      Xs[k4 * 4 + 2][srow] = v.z;
      Xs[k4 * 4 + 3][srow] = v.w;
    }
  }
  __syncthreads();

  const int c0 = ((int)threadIdx.x % CT) * 4;
  const int r0 = ((int)threadIdx.x / CT) * RPT;

  float acc[RPT][4] = {};
#pragma unroll 4
  for (int k = 0; k < 128; ++k) {
    const float4 w = *(const float4*)&W[k * COLS + c0];
#pragma unroll
    for (int j = 0; j < RPT / 4; ++j) {
      const float4 xr = *(const float4*)&Xs[k][r0 + j * 4];
#pragma unroll
      for (int i = 0; i < 4; ++i) {
        float a = (&xr.x)[i];
        acc[j * 4 + i][0] = fmaf(a, w.x, acc[j * 4 + i][0]);
        acc[j * 4 + i][1] = fmaf(a, w.y, acc[j * 4 + i][1]);
        acc[j * 4 + i][2] = fmaf(a, w.z, acc[j * 4 + i][2]);
        acc[j * 4 + i][3] = fmaf(a, w.w, acc[j * 4 + i][3]);
      }
    }
  }

#pragma unroll
  for (int i = 0; i < RPT; ++i) {
    int row = row0 + r0 + i;
    if (row < n) {
      if (HIDDEN) {
        float s = disq[row];
        __half2* Hh = (__half2*)OUT;
        union { __half2 h2[2]; uint2 u; } pk;
        pk.h2[0] = __floats2half2_rn(acc[i][0] * s, acc[i][1] * s);
        pk.h2[1] = __floats2half2_rn(acc[i][2] * s, acc[i][3] * s);
        *(uint2*)&Hh[(long long)row * (COLS / 2) + c0 / 2] = pk.u;
      } else {
        const float4 b = *(const float4*)&bias[c0];
        float4 o = make_float4(acc[i][0] + b.x, acc[i][1] + b.y,
                               acc[i][2] + b.z, acc[i][3] + b.w);
        *(float4*)&((float*)OUT)[(long long)row * COLS + c0] = o;
      }
    }
  }
}

// pull aggregation over fp16 H: one wave per dst, one half2 (2 ch) per lane
__global__ __launch_bounds__(256) void k_aggregate(
    const __half2* __restrict__ Hh, const int* __restrict__ csr_src,
    const int* __restrict__ offsets, const int* __restrict__ counts,
    const float* __restrict__ disq, const float* __restrict__ bias,
    float* __restrict__ X2, int n) {
  int dst = blockIdx.x * 4 + ((int)threadIdx.x >> 6);
  if (dst >= n) return;
  int lane = threadIdx.x & 63;

  float2 acc = __half22float2(Hh[(long long)dst * 64 + lane]);  // self loop
  int beg = offsets[dst];
  int cnt = counts[dst];

  int navail = cnt < 64 ? cnt : 64;
  int myidx = (lane < navail) ? csr_src[beg + lane] : 0;

  int j = 0;
  for (; j + 4 <= navail; j += 4) {
    int s0 = __shfl(myidx, j, 64);
    int s1 = __shfl(myidx, j + 1, 64);
    int s2 = __shfl(myidx, j + 2, 64);
    int s3 = __shfl(myidx, j + 3, 64);
    float2 v0 = __half22float2(Hh[(long long)s0 * 64 + lane]);
    float2 v1 = __half22float2(Hh[(long long)s1 * 64 + lane]);
    float2 v2 = __half22float2(Hh[(long long)s2 * 64 + lane]);
    float2 v3 = __half22float2(Hh[(long long)s3 * 64 + lane]);
    acc.x += v0.x + v1.x + v2.x + v3.x;
    acc.y += v0.y + v1.y + v2.y + v3.y;
  }
  for (; j < navail; ++j) {
    int s = __shfl(myidx, j, 64);
    float2 v = __half22float2(Hh[(long long)s * 64 + lane]);
    acc.x += v.x;
    acc.y += v.y;
  }
  for (int jj = beg + 64; jj < beg + cnt; ++jj) {  // degree>64 fallback
    float2 v = __half22float2(Hh[(long long)csr_src[jj] * 64 + lane]);
    acc.x += v.x;
    acc.y += v.y;
  }

  float s = disq[dst];
  int c = lane * 2;
  float2 b = *(const float2*)&bias[c];
  float2 r;
  r.x = fmaxf(fmaf(s, acc.x, b.x), 0.f);
  r.y = fmaxf(fmaf(s, acc.y, b.y), 0.f);
  *(float2*)&X2[(long long)dst * 128 + c] = r;
}

extern "C" void kernel_launch(void* const* d_in, const int* in_sizes, int n_in,
                              void* d_out, int out_size, void* d_ws, size_t ws_size,
                              hipStream_t stream) {
  (void)n_in; (void)out_size; (void)ws_size;
  const float* x  = (const float*)d_in[0];
  const void*  ei = d_in[1];
  const float* W1 = (const float*)d_in[2];
  const float* b1 = (const float*)d_in[3];
  const float* W2 = (const float*)d_in[4];
  const float* b2 = (const float*)d_in[5];
  const float* Wo = (const float*)d_in[6];
  const float* bo = (const float*)d_in[7];
  float* out = (float*)d_out;

  const int N = in_sizes[0] / 128;
  const int E = in_sizes[1] / 2;
  const int nblk_n = cdiv_i(N, 256);

  char* ws = (char*)d_ws;
  size_t off = 0;
  auto alloc = [&](size_t bytes) {
    void* p = ws + off;
    off += (bytes + 255) & ~(size_t)255;
    return p;
  };
  int*     flag     = (int*)alloc(4);
  int*     counts   = (int*)alloc((size_t)N * 4);
  int*     cursor   = (int*)alloc((size_t)N * 4);
  int*     offsets  = (int*)alloc((size_t)N * 4);
  int*     partials = (int*)alloc((size_t)nblk_n * 4);
  float*   disq     = (float*)alloc((size_t)N * 4);
  int*     csr_src  = (int*)alloc((size_t)E * 4);
  __half2* Hh       = (__half2*)alloc((size_t)N * 64 * 4);
  float*   X2       = (float*)alloc((size_t)N * 128 * 4);

  // --- CSR build + normalization ---
  k_detect<<<1, 64, 0, stream>>>(ei, flag);
  k_zero2<<<nblk_n, 256, 0, stream>>>(counts, cursor, N);
  k_hist<<<cdiv_i(E, 256), 256, 0, stream>>>(ei, flag, counts, E);
  k_disq<<<nblk_n, 256, 0, stream>>>(counts, disq, N);
  k_scan_local<<<nblk_n, 256, 0, stream>>>(counts, offsets, partials, N);
  k_scan_partials<<<1, 256, 0, stream>>>(partials, nblk_n);
  k_scan_add<<<nblk_n, 256, 0, stream>>>(offsets, partials, N);
  k_fill<<<cdiv_i(E, 256), 256, 0, stream>>>(ei, flag, offsets, cursor, csr_src, E);

  const int agg_blocks = cdiv_i(N, 4);

  // Layer 1: 128-col GEMM (fp16 out), 64-row tiles
  k_gemm_t<128, 64, true><<<cdiv_i(N, 64), 256, 0, stream>>>(x, W1, disq, b1, Hh, N);
  k_aggregate<<<agg_blocks, 256, 0, stream>>>(Hh, csr_src, offsets, counts, disq, b1, X2, N);
  // Layer 2
  k_gemm_t<128, 64, true><<<cdiv_i(N, 64), 256, 0, stream>>>(X2, W2, disq, b2, Hh, N);
  k_aggregate<<<agg_blocks, 256, 0, stream>>>(Hh, csr_src, offsets, counts, disq, b2, X2, N);
  // Output layer: 64-col GEMM (f32 out + bias), 128-row tiles
  k_gemm_t<64, 128, false><<<cdiv_i(N, 128), 256, 0, stream>>>(X2, Wo, nullptr, bo, out, N);
}